// Round 11
// baseline (354.196 us; speedup 1.0000x reference)
//
#include <hip/hip_runtime.h>

#define S_SEQ 256
#define N_RES 512
#define CCH   32

typedef __attribute__((ext_vector_type(8))) short bf16x8;
typedef __attribute__((ext_vector_type(4))) float f32x4;
typedef __attribute__((ext_vector_type(2))) unsigned int u32x2;

__device__ __forceinline__ unsigned short f2bf(float x) {
    unsigned int u = __float_as_uint(x);
    return (unsigned short)((u + 0x7FFFu + ((u >> 16) & 1u)) >> 16);
}

__device__ __forceinline__ unsigned int cvtpk(float lo, float hi) {
    unsigned int r;
    asm("v_cvt_pk_bf16_f32 %0, %1, %2" : "=v"(r) : "v"(lo), "v"(hi));
    return r;
}

#define GLOAD_LDS16(gp, lp) __builtin_amdgcn_global_load_lds( \
    (const __attribute__((address_space(1))) unsigned int*)(gp), \
    (__attribute__((address_space(3))) unsigned int*)(lp), 16, 0, 0)

#define BAR()    do { __builtin_amdgcn_s_barrier(); asm volatile("" ::: "memory"); } while (0)
#define WLGKM0() asm volatile("s_waitcnt lgkmcnt(0)" ::: "memory")
#define WVM(n)   asm volatile("s_waitcnt vmcnt(" #n ")" ::: "memory")

// ---------------------------------------------------------------------------
// Kernel 1: LayerNorm + dual projection + mask.
//   A: PLAIN row-major [16384][256] bf16 (read per-lane from L2 by kmain11).
//   B: dual-row 128B image over 128-row tiles (r8/r9-verified, conflict-free):
//      row = n*32+c; tile=row>>7; half=(row>>6)&1; ir=row&63
//      byte = tile*65536 + kt*8192 + ir*128 + ((((half<<2)|q) ^ (ir&7))<<4)
// ---------------------------------------------------------------------------
__global__ __launch_bounds__(256) void prep_ab(
    const float* __restrict__ m, const float* __restrict__ mask,
    const float* __restrict__ gam, const float* __restrict__ bet,
    const float* __restrict__ Wa, const float* __restrict__ ba,
    const float* __restrict__ Wb, const float* __restrict__ bb,
    char* __restrict__ Ag, char* __restrict__ Bg)
{
    __shared__ float WaL[1024], WbL[1024];
    __shared__ float gL[32], btL[32], baL[32], bbL[32];
    __shared__ unsigned short At[32 * 256];
    __shared__ unsigned short Bt[32 * 256];

    const int n = blockIdx.x;
    const int t = threadIdx.x;

    for (int i = t; i < 1024; i += 256) { WaL[i] = Wa[i]; WbL[i] = Wb[i]; }
    if (t < 32) { gL[t] = gam[t]; btL[t] = bet[t]; baL[t] = ba[t]; bbL[t] = bb[t]; }
    __syncthreads();

    const int s = t;
    float mv[32];
    const float* mrow = m + ((size_t)s * N_RES + n) * CCH;
#pragma unroll
    for (int c4 = 0; c4 < 8; c4++) {
        f32x4 v = *(const f32x4*)(mrow + c4 * 4);
        mv[c4 * 4 + 0] = v.x; mv[c4 * 4 + 1] = v.y;
        mv[c4 * 4 + 2] = v.z; mv[c4 * 4 + 3] = v.w;
    }
    float mu = 0.f;
#pragma unroll
    for (int c = 0; c < 32; c++) mu += mv[c];
    mu *= (1.f / 32.f);
    float var = 0.f;
#pragma unroll
    for (int c = 0; c < 32; c++) { float d = mv[c] - mu; var += d * d; }
    var *= (1.f / 32.f);
    float rs = rsqrtf(var + 1e-5f);
    float mh[32];
#pragma unroll
    for (int c = 0; c < 32; c++) mh[c] = (mv[c] - mu) * rs * gL[c] + btL[c];

    const float msk = mask[(size_t)s * N_RES + n];

    f32x4 av[8], bv[8];
#pragma unroll
    for (int cg = 0; cg < 8; cg++) { av[cg] = (f32x4)0.f; bv[cg] = (f32x4)0.f; }
#pragma unroll
    for (int k = 0; k < 32; k++) {
        float x = mh[k];
#pragma unroll
        for (int cg = 0; cg < 8; cg++) {
            f32x4 wa4 = *(const f32x4*)&WaL[k * 32 + cg * 4];
            f32x4 wb4 = *(const f32x4*)&WbL[k * 32 + cg * 4];
            av[cg] += x * wa4;
            bv[cg] += x * wb4;
        }
    }
#pragma unroll
    for (int cg = 0; cg < 8; cg++) {
#pragma unroll
        for (int u = 0; u < 4; u++) {
            int c = cg * 4 + u;
            At[c * 256 + s] = f2bf((av[cg][u] + baL[c]) * msk);
            Bt[c * 256 + s] = f2bf((bv[cg][u] + bbL[c]) * msk);
        }
    }
    __syncthreads();

    // flush (16B chunks): row = n*32+c
    const size_t tbB = (size_t)(n >> 2) * 65536;   // B tile = 128 rows
    const int halfq = ((n >> 1) & 1) << 2;         // (row>>6)&1 << 2
    const int irb = (n & 1) * 32;                  // row&63 base
#pragma unroll
    for (int u = 0; u < 4; u++) {
        int cid = t * 4 + u;             // 1024 chunks: c (32) x 8-seq group g (32)
        int c = cid >> 5, g = cid & 31;
        int kt = g >> 2, q = g & 3;      // s = kt*32 + q*8 + j
        // A plain: [row][s] -> row*512 + g*16
        size_t offA = (size_t)(n * 32 + c) * 512 + (size_t)g * 16;
        size_t offB = tbB + (size_t)kt * 8192 + (size_t)(irb + c) * 128
                    + (size_t)(((halfq | q) ^ (c & 7)) << 4);
        *(uint4*)(Ag + offA) = *(const uint4*)(At + c * 256 + g * 8);
        *(uint4*)(Bg + offB) = *(const uint4*)(Bt + c * 256 + g * 8);
    }
}

// ---------------------------------------------------------------------------
// Kernel 2: Wt3[e][ch][c] = bf16(Wout[(c*32+e)][ch])   (32 x 32 x 32 bf16)
// ---------------------------------------------------------------------------
__global__ __launch_bounds__(256) void kwt(const float* __restrict__ Wout,
                                           unsigned short* __restrict__ Wt3)
{
    int idx = blockIdx.x * 256 + threadIdx.x;   // 32768
    int e = idx >> 10, ch = (idx >> 5) & 31, c = idx & 31;
    Wt3[idx] = f2bf(Wout[(size_t)(c * 32 + e) * 32 + ch]);
}

// ---------------------------------------------------------------------------
// Kernel 3: inv_norm[i][j] = 1 / (sum_s mask[s,i]*mask[s,j] + 1e-3)
// ---------------------------------------------------------------------------
__global__ __launch_bounds__(256) void knorm(const float* __restrict__ mask,
                                             float* __restrict__ inv_norm)
{
    __shared__ float Mi[64][65];
    __shared__ float Mj[64][65];
    const int bi = blockIdx.x >> 3, bj = blockIdx.x & 7;
    const int t = threadIdx.x;
    const int ty = t >> 4, tx = t & 15;

    float acc[4][4];
#pragma unroll
    for (int a = 0; a < 4; a++)
#pragma unroll
        for (int b = 0; b < 4; b++) acc[a][b] = 0.f;

    for (int sc = 0; sc < 4; sc++) {
        for (int e = t; e < 4096; e += 256) {
            int sr = e >> 6, col = e & 63;
            Mi[sr][col] = mask[(size_t)(sc * 64 + sr) * N_RES + bi * 64 + col];
            Mj[sr][col] = mask[(size_t)(sc * 64 + sr) * N_RES + bj * 64 + col];
        }
        __syncthreads();
        for (int sp = 0; sp < 64; sp++) {
#pragma unroll
            for (int a = 0; a < 4; a++)
#pragma unroll
                for (int b = 0; b < 4; b++)
                    acc[a][b] += Mi[sp][ty * 4 + a] * Mj[sp][tx * 4 + b];
        }
        __syncthreads();
    }
#pragma unroll
    for (int a = 0; a < 4; a++)
#pragma unroll
        for (int b = 0; b < 4; b++) {
            int i = bi * 64 + ty * 4 + a;
            int j = bj * 64 + tx * 4 + b;
            inv_norm[(size_t)i * N_RES + j] = 1.f / (acc[a][b] + 1e-3f);
        }
}

// ---------------------------------------------------------------------------
// Kernel 11: 128x128 tile, 4 waves x (64x64), BK=32. A-frags read PER-LANE
// from global (L2-resident stripe) -> zero A LDS traffic. B: dbuf 2x8KB
// staged via global_load_lds, conflict-free image reads. LDS 33KB ->
// 4 blocks/CU. WVM(2) gates B staging only (af deps are compiler-tracked).
// Epilogue: r9-verified (G 16 pairs, f(e)=(e>>1)&3 swizzle, K split 4 ways).
// ---------------------------------------------------------------------------
__global__ __launch_bounds__(256, 4) void kmain11(
    const char* __restrict__ Ag, const char* __restrict__ Bg,
    const unsigned short* __restrict__ Wt3, const float* __restrict__ inv_norm,
    const float* __restrict__ bout, float* __restrict__ out)
{
    __shared__ __align__(16) char sm[33024];   // B dbuf [0,16384); epi G [0,33024)

    const int bid = blockIdx.x;                // 16384 = 128 TI x 128 TJ
    const int xcd = bid & 7;
    const int xidx = bid >> 3;                 // 0..2047
    const int TI = xcd * 16 + ((xidx >> 5) & 15);
    const int TJ = (xidx >> 9) * 32 + (xidx & 31);

    const int t = threadIdx.x;
    const int lane = t & 63, wid = t >> 6;
    const int wr = wid >> 1, wc = wid & 1;     // wave tile 64x64
    const int rl = lane & 15, h4 = lane >> 4;

    const char* pA = Ag + (size_t)TI * 65536;  // 128 rows x 512 B
    const char* pb = Bg + (size_t)TJ * 65536;  // B image tile

#define SB(kt) do { \
    char* db_ = sm + (((kt) & 1) * 8192); \
    GLOAD_LDS16(pb + (kt) * 8192 + t * 16,        db_ + t * 16); \
    GLOAD_LDS16(pb + (kt) * 8192 + 4096 + t * 16, db_ + 4096 + t * 16); \
} while (0)

    // A per-lane frag offsets: row = wr*64 + am*16 + rl, bytes row*512 + kt*64 + h4*16
    const int abase = (wr * 64 + rl) * 512 + h4 * 16;   // + am*8192 + kt*64
    // B frag base (image): + bn*2048 + (kt&1)*8192
    const int bbase = rl * 128 + ((((wc << 2) | h4) ^ (rl & 7)) << 4);

    f32x4 acc[4][4];
#pragma unroll
    for (int a = 0; a < 4; a++)
#pragma unroll
        for (int b = 0; b < 4; b++) acc[a][b] = (f32x4)0.f;

    // prologue: A frags for kt=0 (reg), B stage kt=0,1 (LDS)
    bf16x8 af[4];
#pragma unroll
    for (int am = 0; am < 4; am++)
        af[am] = *(const bf16x8*)(pA + abase + am * 8192);
    SB(0);
    SB(1);

#pragma unroll
    for (int kt = 0; kt < 8; kt++) {
        if (kt < 7) { WVM(2); } else { WVM(0); }   // S(kt) retired; S(kt+1) in flight
        BAR();                                     // B(kt) visible to all waves
        const char* buf = sm + ((kt & 1) * 8192);
        bf16x8 bfr[4];
#pragma unroll
        for (int bn = 0; bn < 4; bn++)
            bfr[bn] = *(const bf16x8*)(buf + bbase + bn * 2048);
        __builtin_amdgcn_s_setprio(1);
#pragma unroll
        for (int am = 0; am < 4; am++)
#pragma unroll
            for (int bn = 0; bn < 4; bn++)
                acc[am][bn] = __builtin_amdgcn_mfma_f32_16x16x32_bf16(
                    af[am], bfr[bn], acc[am][bn], 0, 0, 0);
        __builtin_amdgcn_s_setprio(0);
        // issue next-KT A frags (register dbuf via SSA rename; af dead here)
        if (kt < 7) {
#pragma unroll
            for (int am = 0; am < 4; am++)
                af[am] = *(const bf16x8*)(pA + abase + am * 8192 + (kt + 1) * 64);
        }
        BAR();                                     // all waves' B reads retired
        if (kt <= 5) SB(kt + 2);                   // overwrites buf(kt) (safe)
    }
#undef SB

    // ---- epilogue: G write (16 pairs x 2064B, f(e)=(e>>1)&3 swizzle) ----
#pragma unroll
    for (int am = 0; am < 4; am++) {
        const int cs = ((am & 1) << 1) + (h4 >> 1);
#pragma unroll
        for (int bn = 0; bn < 4; bn++) {
            const int p = (wr * 2 + (am >> 1)) * 4 + wc * 2 + (bn >> 1);
            const int e = ((bn & 1) << 4) + rl;
            u32x2 wv;
            wv[0] = cvtpk(acc[am][bn][0], acc[am][bn][1]);
            wv[1] = cvtpk(acc[am][bn][2], acc[am][bn][3]);
            *(u32x2*)(sm + p * 2064 + e * 64 +
                      ((cs ^ ((e >> 1) & 3)) << 4) + ((h4 & 1) << 3)) = wv;
        }
    }
    WLGKM0();                                  // G writes visible
    BAR();

    // ---- second GEMM: wave = K quarter kq; 16 pairs x 32 ch each ----
    const int kq = wid;
    f32x4 ae0 = (f32x4)0.f, ae1 = (f32x4)0.f;
    const char* grow = sm + rl * 2064;
#pragma unroll
    for (int es = 0; es < 8; es++) {
        const int e = kq * 8 + es;
        bf16x8 ga = *(const bf16x8*)(grow + e * 64 + ((h4 ^ ((e >> 1) & 3)) << 4));
        bf16x8 wb0 = *(const bf16x8*)(Wt3 + (size_t)e * 1024 + rl * 32 + h4 * 8);
        bf16x8 wb1 = *(const bf16x8*)(Wt3 + (size_t)e * 1024 + (16 + rl) * 32 + h4 * 8);
        ae0 = __builtin_amdgcn_mfma_f32_16x16x32_bf16(ga, wb0, ae0, 0, 0, 0);
        ae1 = __builtin_amdgcn_mfma_f32_16x16x32_bf16(ga, wb1, ae1, 0, 0, 0);
    }
    BAR();                                     // ga consumed -> G head reusable

    // ---- partials ps[kq][pair=h4*4+r][ch] (stride 34), overlays G[0,8704) ----
    float* ps = (float*)sm;
#pragma unroll
    for (int r = 0; r < 4; r++) {
        ps[(kq * 16 + h4 * 4 + r) * 34 + rl]      = ae0[r];
        ps[(kq * 16 + h4 * 4 + r) * 34 + 16 + rl] = ae1[r];
    }
    WLGKM0();                                  // ps writes visible
    BAR();

    // ---- reduce 4 K-quarters + bias + mask-norm + coalesced store ----
#pragma unroll
    for (int u = 0; u < 2; u++) {
        const int idx = u * 256 + t;
        const int p = idx >> 5, ch = idx & 31;
        float v = 0.f;
#pragma unroll
        for (int k2 = 0; k2 < 4; k2++)
            v += ps[(k2 * 16 + p) * 34 + ch];
        const int i = TI * 4 + (p >> 2), j = TJ * 4 + (p & 3);
        out[((size_t)(i * N_RES + j)) * CCH + ch] =
            (v + bout[ch]) * inv_norm[(size_t)i * N_RES + j];
    }
}

// ---------------------------------------------------------------------------
extern "C" void kernel_launch(void* const* d_in, const int* in_sizes, int n_in,
                              void* d_out, int out_size, void* d_ws, size_t ws_size,
                              hipStream_t stream)
{
    const float* m    = (const float*)d_in[0];
    const float* mask = (const float*)d_in[1];
    const float* gam  = (const float*)d_in[2];
    const float* bet  = (const float*)d_in[3];
    const float* Wa   = (const float*)d_in[4];
    const float* ba   = (const float*)d_in[5];
    const float* Wb   = (const float*)d_in[6];
    const float* bb   = (const float*)d_in[7];
    const float* Wout = (const float*)d_in[8];
    const float* bout = (const float*)d_in[9];
    float* out = (float*)d_out;

    char* ws = (char*)d_ws;
    char* Ag = ws;                                            //  8,388,608 B (plain)
    char* Bg = ws + 8388608;                                  //  8,388,608 B (image)
    unsigned short* Wt3 = (unsigned short*)(ws + 16777216);   //     65,536 B
    float* inv_norm = (float*)(ws + 16842752);                //  1,048,576 B

    prep_ab<<<dim3(N_RES), dim3(256), 0, stream>>>(m, mask, gam, bet, Wa, ba, Wb, bb, Ag, Bg);
    kwt<<<dim3(128), dim3(256), 0, stream>>>(Wout, Wt3);
    knorm<<<dim3(64), dim3(256), 0, stream>>>(mask, inv_norm);
    kmain11<<<dim3(16384), dim3(256), 0, stream>>>(Ag, Bg, Wt3, inv_norm, bout, out);
}

// Round 15
// 201.937 us; speedup vs baseline: 1.7540x; 1.7540x over previous
//
#include <hip/hip_runtime.h>

#define S_SEQ 256
#define N_RES 512
#define CCH   32

typedef __attribute__((ext_vector_type(8))) short bf16x8;
typedef __attribute__((ext_vector_type(4))) float f32x4;
typedef __attribute__((ext_vector_type(2))) unsigned int u32x2;

__device__ __forceinline__ unsigned short f2bf(float x) {
    unsigned int u = __float_as_uint(x);
    return (unsigned short)((u + 0x7FFFu + ((u >> 16) & 1u)) >> 16);
}

#define GLOAD_LDS16(gp, lp) __builtin_amdgcn_global_load_lds( \
    (const __attribute__((address_space(1))) unsigned int*)(gp), \
    (__attribute__((address_space(3))) unsigned int*)(lp), 16, 0, 0)

#define BAR()    do { __builtin_amdgcn_s_barrier(); asm volatile("" ::: "memory"); } while (0)
#define WLGKM0() asm volatile("s_waitcnt lgkmcnt(0)" ::: "memory")
#define WVM(n)   asm volatile("s_waitcnt vmcnt(" #n ")" ::: "memory")

// ---------------------------------------------------------------------------
// Kernel 1: LayerNorm + dual projection + mask. A and B both written as the
// dual-row 128B image over 128-row tiles (r8/r9-verified, conflict-free):
//   row = n*32+c; tile=row>>7; half=(row>>6)&1; ir=row&63
//   byte = tile*65536 + kt*8192 + ir*128 + ((((half<<2)|q) ^ (ir&7))<<4)
// ---------------------------------------------------------------------------
__global__ __launch_bounds__(256) void prep_ab(
    const float* __restrict__ m, const float* __restrict__ mask,
    const float* __restrict__ gam, const float* __restrict__ bet,
    const float* __restrict__ Wa, const float* __restrict__ ba,
    const float* __restrict__ Wb, const float* __restrict__ bb,
    char* __restrict__ Ag, char* __restrict__ Bg)
{
    __shared__ float WaL[1024], WbL[1024];
    __shared__ float gL[32], btL[32], baL[32], bbL[32];
    __shared__ unsigned short At[32 * 256];
    __shared__ unsigned short Bt[32 * 256];

    const int n = blockIdx.x;
    const int t = threadIdx.x;

    for (int i = t; i < 1024; i += 256) { WaL[i] = Wa[i]; WbL[i] = Wb[i]; }
    if (t < 32) { gL[t] = gam[t]; btL[t] = bet[t]; baL[t] = ba[t]; bbL[t] = bb[t]; }
    __syncthreads();

    const int s = t;
    float mv[32];
    const float* mrow = m + ((size_t)s * N_RES + n) * CCH;
#pragma unroll
    for (int c4 = 0; c4 < 8; c4++) {
        f32x4 v = *(const f32x4*)(mrow + c4 * 4);
        mv[c4 * 4 + 0] = v.x; mv[c4 * 4 + 1] = v.y;
        mv[c4 * 4 + 2] = v.z; mv[c4 * 4 + 3] = v.w;
    }
    float mu = 0.f;
#pragma unroll
    for (int c = 0; c < 32; c++) mu += mv[c];
    mu *= (1.f / 32.f);
    float var = 0.f;
#pragma unroll
    for (int c = 0; c < 32; c++) { float d = mv[c] - mu; var += d * d; }
    var *= (1.f / 32.f);
    float rs = rsqrtf(var + 1e-5f);
    float mh[32];
#pragma unroll
    for (int c = 0; c < 32; c++) mh[c] = (mv[c] - mu) * rs * gL[c] + btL[c];

    const float msk = mask[(size_t)s * N_RES + n];

    f32x4 av[8], bv[8];
#pragma unroll
    for (int cg = 0; cg < 8; cg++) { av[cg] = (f32x4)0.f; bv[cg] = (f32x4)0.f; }
#pragma unroll
    for (int k = 0; k < 32; k++) {
        float x = mh[k];
#pragma unroll
        for (int cg = 0; cg < 8; cg++) {
            f32x4 wa4 = *(const f32x4*)&WaL[k * 32 + cg * 4];
            f32x4 wb4 = *(const f32x4*)&WbL[k * 32 + cg * 4];
            av[cg] += x * wa4;
            bv[cg] += x * wb4;
        }
    }
#pragma unroll
    for (int cg = 0; cg < 8; cg++) {
#pragma unroll
        for (int u = 0; u < 4; u++) {
            int c = cg * 4 + u;
            At[c * 256 + s] = f2bf((av[cg][u] + baL[c]) * msk);
            Bt[c * 256 + s] = f2bf((bv[cg][u] + bbL[c]) * msk);
        }
    }
    __syncthreads();

    // flush (16B chunks): row = n*32+c
    const size_t tbase = (size_t)(n >> 2) * 65536;     // tile = 128 rows
    const int halfq = ((n >> 1) & 1) << 2;             // (row>>6)&1 <<2
    const int irb = (n & 1) * 32;                      // ir = (row&63) base
#pragma unroll
    for (int u = 0; u < 4; u++) {
        int cid = t * 4 + u;             // 1024 chunks: c (32) x 8-seq group g (32)
        int c = cid >> 5, g = cid & 31;
        int kt = g >> 2, q = g & 3;      // s = kt*32 + q*8 + j
        size_t off = tbase + (size_t)kt * 8192 + (size_t)(irb + c) * 128
                   + (size_t)(((halfq | q) ^ (c & 7)) << 4);
        *(uint4*)(Ag + off) = *(const uint4*)(At + c * 256 + g * 8);
        *(uint4*)(Bg + off) = *(const uint4*)(Bt + c * 256 + g * 8);
    }
}

// ---------------------------------------------------------------------------
// Kernel 2: Wt3[e][ch][c] = bf16(Wout[(c*32+e)][ch])   (32 x 32 x 32 bf16)
// ---------------------------------------------------------------------------
__global__ __launch_bounds__(256) void kwt(const float* __restrict__ Wout,
                                           unsigned short* __restrict__ Wt3)
{
    int idx = blockIdx.x * 256 + threadIdx.x;   // 32768
    int e = idx >> 10, ch = (idx >> 5) & 31, c = idx & 31;
    Wt3[idx] = f2bf(Wout[(size_t)(c * 32 + e) * 32 + ch]);
}

// ---------------------------------------------------------------------------
// Kernel 3: inv_norm[i][j] = 1 / (sum_s mask[s,i]*mask[s,j] + 1e-3)
// ---------------------------------------------------------------------------
__global__ __launch_bounds__(256) void knorm(const float* __restrict__ mask,
                                             float* __restrict__ inv_norm)
{
    __shared__ float Mi[64][65];
    __shared__ float Mj[64][65];
    const int bi = blockIdx.x >> 3, bj = blockIdx.x & 7;
    const int t = threadIdx.x;
    const int ty = t >> 4, tx = t & 15;

    float acc[4][4];
#pragma unroll
    for (int a = 0; a < 4; a++)
#pragma unroll
        for (int b = 0; b < 4; b++) acc[a][b] = 0.f;

    for (int sc = 0; sc < 4; sc++) {
        for (int e = t; e < 4096; e += 256) {
            int sr = e >> 6, col = e & 63;
            Mi[sr][col] = mask[(size_t)(sc * 64 + sr) * N_RES + bi * 64 + col];
            Mj[sr][col] = mask[(size_t)(sc * 64 + sr) * N_RES + bj * 64 + col];
        }
        __syncthreads();
        for (int sp = 0; sp < 64; sp++) {
#pragma unroll
            for (int a = 0; a < 4; a++)
#pragma unroll
                for (int b = 0; b < 4; b++)
                    acc[a][b] += Mi[sp][ty * 4 + a] * Mj[sp][tx * 4 + b];
        }
        __syncthreads();
    }
#pragma unroll
    for (int a = 0; a < 4; a++)
#pragma unroll
        for (int b = 0; b < 4; b++) {
            int i = bi * 64 + ty * 4 + a;
            int j = bj * 64 + tx * 4 + b;
            inv_norm[(size_t)i * N_RES + j] = 1.f / (acc[a][b] + 1e-3f);
        }
}

// ---------------------------------------------------------------------------
// Kernel 9 (verified best, resubmitted byte-identical): 128x128 tile,
// 4 waves x 64x64, dbuf 2x16KB, 4 blocks/CU, counted vmcnt(4), setprio,
// G layout f(e)=(e>>1)&3, f2bf dump, loop-form reduce.
// ---------------------------------------------------------------------------
__global__ __launch_bounds__(256, 4) void kmain9(
    const char* __restrict__ Ag, const char* __restrict__ Bg,
    const unsigned short* __restrict__ Wt3, const float* __restrict__ inv_norm,
    const float* __restrict__ bout, float* __restrict__ out)
{
    __shared__ __align__(16) char sm[33024];   // dbuf [0,32768); epi G [0,33024)

    const int bid = blockIdx.x;                // 16384 = 128 TI x 128 TJ
    const int xcd = bid & 7;
    const int xidx = bid >> 3;                 // 0..2047
    const int TI = xcd * 16 + ((xidx >> 5) & 15);
    const int TJ = (xidx >> 9) * 32 + (xidx & 31);

    const int t = threadIdx.x;
    const int lane = t & 63, wid = t >> 6;
    const int wr = wid >> 1, wc = wid & 1;     // wave tile 64x64
    const int rl = lane & 15, h4 = lane >> 4;

    const char* pa = Ag + (size_t)TI * 65536;
    const char* pb = Bg + (size_t)TJ * 65536;

#define SH(kt) do { \
    char* db_ = sm + (((kt) & 1) * 16384); \
    GLOAD_LDS16(pa + (kt) * 8192 + t * 16,        db_ + t * 16); \
    GLOAD_LDS16(pa + (kt) * 8192 + 4096 + t * 16, db_ + 4096 + t * 16); \
    GLOAD_LDS16(pb + (kt) * 8192 + t * 16,        db_ + 8192 + t * 16); \
    GLOAD_LDS16(pb + (kt) * 8192 + 4096 + t * 16, db_ + 12288 + t * 16); \
} while (0)

    // lane-constant frag offsets (dual-row image: half = wr / wc)
    const int abase = rl * 128 + (((((wr << 2) | h4)) ^ (rl & 7)) << 4);        // + am*2048
    const int bbase = 8192 + rl * 128 + (((((wc << 2) | h4)) ^ (rl & 7)) << 4); // + bn*2048

    f32x4 acc[4][4];
#pragma unroll
    for (int a = 0; a < 4; a++)
#pragma unroll
        for (int b = 0; b < 4; b++) acc[a][b] = (f32x4)0.f;

    SH(0);
    SH(1);

#pragma unroll
    for (int kt = 0; kt < 8; kt++) {
        if (kt < 7) { WVM(4); } else { WVM(0); }
        BAR();                                 // kt's data visible to all waves
        const char* buf = sm + ((kt & 1) * 16384);
        bf16x8 af[4], bfr[4];
#pragma unroll
        for (int am = 0; am < 4; am++)
            af[am] = *(const bf16x8*)(buf + abase + am * 2048);
#pragma unroll
        for (int bn = 0; bn < 4; bn++)
            bfr[bn] = *(const bf16x8*)(buf + bbase + bn * 2048);
        __builtin_amdgcn_s_setprio(1);
#pragma unroll
        for (int am = 0; am < 4; am++)
#pragma unroll
            for (int bn = 0; bn < 4; bn++)
                acc[am][bn] = __builtin_amdgcn_mfma_f32_16x16x32_bf16(
                    af[am], bfr[bn], acc[am][bn], 0, 0, 0);
        __builtin_amdgcn_s_setprio(0);
        BAR();                                 // all waves' frags consumed
        if (kt <= 5) SH(kt + 2);               // overwrites kt's buffer (safe)
    }
#undef SH

    // ---- epilogue: G write (16 pairs x 2064B, f(e)=(e>>1)&3 swizzle) ----
#pragma unroll
    for (int am = 0; am < 4; am++) {
        const int cs = ((am & 1) << 1) + (h4 >> 1);
#pragma unroll
        for (int bn = 0; bn < 4; bn++) {
            const int p = (wr * 2 + (am >> 1)) * 4 + wc * 2 + (bn >> 1);
            const int e = ((bn & 1) << 4) + rl;
            unsigned int lo = (unsigned int)f2bf(acc[am][bn][0]) |
                              ((unsigned int)f2bf(acc[am][bn][1]) << 16);
            unsigned int hi = (unsigned int)f2bf(acc[am][bn][2]) |
                              ((unsigned int)f2bf(acc[am][bn][3]) << 16);
            u32x2 wv; wv[0] = lo; wv[1] = hi;
            *(u32x2*)(sm + p * 2064 + e * 64 +
                      ((cs ^ ((e >> 1) & 3)) << 4) + ((h4 & 1) << 3)) = wv;
        }
    }
    WLGKM0();                                  // G writes visible
    BAR();

    // ---- second GEMM: wave = K quarter kq; 16 pairs x 32 ch each ----
    const int kq = wid;
    f32x4 ae0 = (f32x4)0.f, ae1 = (f32x4)0.f;
    const char* grow = sm + rl * 2064;
#pragma unroll
    for (int es = 0; es < 8; es++) {
        const int e = kq * 8 + es;
        bf16x8 ga = *(const bf16x8*)(grow + e * 64 + ((h4 ^ ((e >> 1) & 3)) << 4));
        bf16x8 wb0 = *(const bf16x8*)(Wt3 + (size_t)e * 1024 + rl * 32 + h4 * 8);
        bf16x8 wb1 = *(const bf16x8*)(Wt3 + (size_t)e * 1024 + (16 + rl) * 32 + h4 * 8);
        ae0 = __builtin_amdgcn_mfma_f32_16x16x32_bf16(ga, wb0, ae0, 0, 0, 0);
        ae1 = __builtin_amdgcn_mfma_f32_16x16x32_bf16(ga, wb1, ae1, 0, 0, 0);
    }
    BAR();                                     // ga consumed -> G head reusable

    // ---- partials ps[kq][pair=h4*4+r][ch] (stride 34), overlays G[0,8704) ----
    float* ps = (float*)sm;
#pragma unroll
    for (int r = 0; r < 4; r++) {
        ps[(kq * 16 + h4 * 4 + r) * 34 + rl]      = ae0[r];
        ps[(kq * 16 + h4 * 4 + r) * 34 + 16 + rl] = ae1[r];
    }
    WLGKM0();                                  // ps writes visible
    BAR();

    // ---- reduce 4 K-quarters + bias + mask-norm + coalesced store ----
#pragma unroll
    for (int u = 0; u < 2; u++) {
        const int idx = u * 256 + t;
        const int p = idx >> 5, ch = idx & 31;
        float v = 0.f;
#pragma unroll
        for (int k2 = 0; k2 < 4; k2++)
            v += ps[(k2 * 16 + p) * 34 + ch];
        const int i = TI * 4 + (p >> 2), j = TJ * 4 + (p & 3);
        out[((size_t)(i * N_RES + j)) * CCH + ch] =
            (v + bout[ch]) * inv_norm[(size_t)i * N_RES + j];
    }
}

// ---------------------------------------------------------------------------
extern "C" void kernel_launch(void* const* d_in, const int* in_sizes, int n_in,
                              void* d_out, int out_size, void* d_ws, size_t ws_size,
                              hipStream_t stream)
{
    const float* m    = (const float*)d_in[0];
    const float* mask = (const float*)d_in[1];
    const float* gam  = (const float*)d_in[2];
    const float* bet  = (const float*)d_in[3];
    const float* Wa   = (const float*)d_in[4];
    const float* ba   = (const float*)d_in[5];
    const float* Wb   = (const float*)d_in[6];
    const float* bb   = (const float*)d_in[7];
    const float* Wout = (const float*)d_in[8];
    const float* bout = (const float*)d_in[9];
    float* out = (float*)d_out;

    char* ws = (char*)d_ws;
    char* Ag = ws;                                            //  8,388,608 B
    char* Bg = ws + 8388608;                                  //  8,388,608 B
    unsigned short* Wt3 = (unsigned short*)(ws + 16777216);   //     65,536 B
    float* inv_norm = (float*)(ws + 16842752);                //  1,048,576 B

    prep_ab<<<dim3(N_RES), dim3(256), 0, stream>>>(m, mask, gam, bet, Wa, ba, Wb, bb, Ag, Bg);
    kwt<<<dim3(128), dim3(256), 0, stream>>>(Wout, Wt3);
    knorm<<<dim3(64), dim3(256), 0, stream>>>(mask, inv_norm);
    kmain9<<<dim3(16384), dim3(256), 0, stream>>>(Ag, Bg, Wt3, inv_norm, bout, out);
}